// Round 2
// baseline (2868.408 us; speedup 1.0000x reference)
//
#include <hip/hip_runtime.h>
#include <stdint.h>

// MultiViewHyperConvNetwork: P=200000, U=50000, NNZ=2e6, D=64, 3 layers,
// dropout 0.5 (training) with JAX threefry PRNG (partitionable path),
// key(42) fold_in(layer).
//
// out = (pois + sum_l x_l) / 4, where per layer:
//   msg  = HG_up @ x      [U,64]   (COO scatter-atomic)
//   prop = HG_pu @ msg    [P,64]   (COO scatter-atomic)
//   x    = dropout(prop + x) * 2-or-0
//
// Dropout mask (JAX >=0.4.30, jax_threefry_partitionable=True):
//   word_j = o0 ^ o1 where (o0,o1) = threefry2x32(key_l, (0, j)), j = flat idx
//   keep iff bit31(word_j) == 0;  kept values scaled by 1/keep = 2.

#define DIM 64
#define NUM_U 50000

__host__ __device__ __forceinline__ uint32_t rotl32(uint32_t v, int d) {
    return (v << d) | (v >> (32 - d));
}

// Threefry-2x32, 20 rounds — bit-exact match to JAX's threefry2x32_p.
__host__ __device__ __forceinline__ void threefry2x32(uint32_t k0, uint32_t k1,
                                                      uint32_t& x0, uint32_t& x1) {
    const uint32_t ks0 = k0, ks1 = k1, ks2 = k0 ^ k1 ^ 0x1BD11BDAu;
    x0 += ks0; x1 += ks1;
    x0 += x1; x1 = rotl32(x1, 13); x1 ^= x0;
    x0 += x1; x1 = rotl32(x1, 15); x1 ^= x0;
    x0 += x1; x1 = rotl32(x1, 26); x1 ^= x0;
    x0 += x1; x1 = rotl32(x1, 6);  x1 ^= x0;
    x0 += ks1; x1 += ks2 + 1u;
    x0 += x1; x1 = rotl32(x1, 17); x1 ^= x0;
    x0 += x1; x1 = rotl32(x1, 29); x1 ^= x0;
    x0 += x1; x1 = rotl32(x1, 16); x1 ^= x0;
    x0 += x1; x1 = rotl32(x1, 24); x1 ^= x0;
    x0 += ks2; x1 += ks0 + 2u;
    x0 += x1; x1 = rotl32(x1, 13); x1 ^= x0;
    x0 += x1; x1 = rotl32(x1, 15); x1 ^= x0;
    x0 += x1; x1 = rotl32(x1, 26); x1 ^= x0;
    x0 += x1; x1 = rotl32(x1, 6);  x1 ^= x0;
    x0 += ks0; x1 += ks1 + 3u;
    x0 += x1; x1 = rotl32(x1, 17); x1 ^= x0;
    x0 += x1; x1 = rotl32(x1, 29); x1 ^= x0;
    x0 += x1; x1 = rotl32(x1, 16); x1 ^= x0;
    x0 += x1; x1 = rotl32(x1, 24); x1 ^= x0;
    x0 += ks1; x1 += ks2 + 4u;
    x0 += x1; x1 = rotl32(x1, 13); x1 ^= x0;
    x0 += x1; x1 = rotl32(x1, 15); x1 ^= x0;
    x0 += x1; x1 = rotl32(x1, 26); x1 ^= x0;
    x0 += x1; x1 = rotl32(x1, 6);  x1 ^= x0;
    x0 += ks2; x1 += ks0 + 5u;
}

__global__ void init_kernel(const float4* __restrict__ pois, float4* __restrict__ x,
                            float4* __restrict__ out, int n4) {
    int i = blockIdx.x * blockDim.x + threadIdx.x;
    if (i < n4) {
        float4 v = pois[i];
        x[i] = v;
        out[i] = make_float4(0.25f * v.x, 0.25f * v.y, 0.25f * v.z, 0.25f * v.w);
    }
}

// COO SpMM scatter: one wave (64 lanes) per nonzero; lane d owns column d.
__global__ void spmm_scatter(const int* __restrict__ rows, const int* __restrict__ cols,
                             const float* __restrict__ vals, const float* __restrict__ x,
                             float* __restrict__ out, int nnz) {
    int gid = blockIdx.x * blockDim.x + threadIdx.x;
    int nz = gid >> 6;
    int lane = gid & 63;
    if (nz < nnz) {
        int r = rows[nz];
        int c = cols[nz];
        float v = vals[nz];
        atomicAdd(&out[(size_t)r * DIM + lane], v * x[(size_t)c * DIM + lane]);
    }
}

// Fused: x = dropout(prop + x), out += 0.25 * x.
// Partitionable threefry: element j keeps iff bit31(o0^o1)==0 for block (0,j).
__global__ void layer_update(const float4* __restrict__ prop, float4* __restrict__ x,
                             float4* __restrict__ out, uint32_t k0, uint32_t k1,
                             int n4) {
    int t = blockIdx.x * blockDim.x + threadIdx.x;
    if (t >= n4) return;
    float4 p = prop[t];
    float4 xv = x[t];
    float4 o = out[t];
    float a[4] = {p.x + xv.x, p.y + xv.y, p.z + xv.z, p.w + xv.w};
    uint32_t base = 4u * (uint32_t)t;
#pragma unroll
    for (int i = 0; i < 4; ++i) {
        uint32_t hi = 0u, lo = base + (uint32_t)i;
        threefry2x32(k0, k1, hi, lo);
        uint32_t w = hi ^ lo;
        a[i] = (w & 0x80000000u) ? 0.0f : 2.0f * a[i];
    }
    float4 nx = make_float4(a[0], a[1], a[2], a[3]);
    x[t] = nx;
    out[t] = make_float4(o.x + 0.25f * nx.x, o.y + 0.25f * nx.y,
                         o.z + 0.25f * nx.z, o.w + 0.25f * nx.w);
}

extern "C" void kernel_launch(void* const* d_in, const int* in_sizes, int n_in,
                              void* d_out, int out_size, void* d_ws, size_t ws_size,
                              hipStream_t stream) {
    const float* pois    = (const float*)d_in[0];
    const int*   up_rows = (const int*)d_in[1];
    const int*   up_cols = (const int*)d_in[2];
    const float* up_vals = (const float*)d_in[3];
    const int*   pu_rows = (const int*)d_in[4];
    const int*   pu_cols = (const int*)d_in[5];
    const float* pu_vals = (const float*)d_in[6];
    float* out = (float*)d_out;

    const int n   = in_sizes[0];        // P*DIM = 12,800,000
    const int nnz = in_sizes[1];        // 2,000,000
    const int mU  = NUM_U * DIM;        // 3,200,000

    float* x    = (float*)d_ws;         // [P*DIM]
    float* msg  = x + n;                // [U*DIM]
    float* prop = msg + mU;             // [P*DIM]

    const int n4 = n / 4;
    init_kernel<<<(n4 + 255) / 256, 256, 0, stream>>>(
        (const float4*)pois, (float4*)x, (float4*)out, n4);

    const int spmm_blocks = (int)(((long long)nnz * 64 + 255) / 256);

    for (int l = 0; l < 3; ++l) {
        hipMemsetAsync(msg, 0, (size_t)mU * sizeof(float), stream);
        spmm_scatter<<<spmm_blocks, 256, 0, stream>>>(
            up_rows, up_cols, up_vals, x, msg, nnz);
        hipMemsetAsync(prop, 0, (size_t)n * sizeof(float), stream);
        spmm_scatter<<<spmm_blocks, 256, 0, stream>>>(
            pu_rows, pu_cols, pu_vals, msg, prop, nnz);

        // key_l = threefry((0,42), (0,l)) — host-side, same every call.
        uint32_t kk0 = 0u, kk1 = (uint32_t)l;
        threefry2x32(0u, 42u, kk0, kk1);
        layer_update<<<(n4 + 255) / 256, 256, 0, stream>>>(
            (const float4*)prop, (float4*)x, (float4*)out, kk0, kk1, n4);
    }
}

// Round 4
// 1712.816 us; speedup vs baseline: 1.6747x; 1.6747x over previous
//
#include <hip/hip_runtime.h>
#include <stdint.h>

// MultiViewHyperConvNetwork: P=200000, U=50000, NNZ=2e6, D=64, 3 layers,
// dropout 0.5 (JAX partitionable threefry), key(42) fold_in(layer).
//
// Round-2 structure: build CSR for both COO matrices on device each call
// (counting sort), then gather-style SpMM (no atomics):
//   msg  = HG_up @ x          one wave per U-row, reg accumulate
//   x    = dropout(HG_pu@msg + x); out += x/4   fused, one wave per P-row

#define DIM 64
#define SCAN_BLOCK 256
#define SCAN_ITEMS 4
#define SCAN_CHUNK (SCAN_BLOCK * SCAN_ITEMS)

__host__ __device__ __forceinline__ uint32_t rotl32(uint32_t v, int d) {
    return (v << d) | (v >> (32 - d));
}

// Threefry-2x32, 20 rounds — bit-exact match to JAX's threefry2x32_p.
__host__ __device__ __forceinline__ void threefry2x32(uint32_t k0, uint32_t k1,
                                                      uint32_t& x0, uint32_t& x1) {
    const uint32_t ks0 = k0, ks1 = k1, ks2 = k0 ^ k1 ^ 0x1BD11BDAu;
    x0 += ks0; x1 += ks1;
    x0 += x1; x1 = rotl32(x1, 13); x1 ^= x0;
    x0 += x1; x1 = rotl32(x1, 15); x1 ^= x0;
    x0 += x1; x1 = rotl32(x1, 26); x1 ^= x0;
    x0 += x1; x1 = rotl32(x1, 6);  x1 ^= x0;
    x0 += ks1; x1 += ks2 + 1u;
    x0 += x1; x1 = rotl32(x1, 17); x1 ^= x0;
    x0 += x1; x1 = rotl32(x1, 29); x1 ^= x0;
    x0 += x1; x1 = rotl32(x1, 16); x1 ^= x0;
    x0 += x1; x1 = rotl32(x1, 24); x1 ^= x0;
    x0 += ks2; x1 += ks0 + 2u;
    x0 += x1; x1 = rotl32(x1, 13); x1 ^= x0;
    x0 += x1; x1 = rotl32(x1, 15); x1 ^= x0;
    x0 += x1; x1 = rotl32(x1, 26); x1 ^= x0;
    x0 += x1; x1 = rotl32(x1, 6);  x1 ^= x0;
    x0 += ks0; x1 += ks1 + 3u;
    x0 += x1; x1 = rotl32(x1, 17); x1 ^= x0;
    x0 += x1; x1 = rotl32(x1, 29); x1 ^= x0;
    x0 += x1; x1 = rotl32(x1, 16); x1 ^= x0;
    x0 += x1; x1 = rotl32(x1, 24); x1 ^= x0;
    x0 += ks1; x1 += ks2 + 4u;
    x0 += x1; x1 = rotl32(x1, 13); x1 ^= x0;
    x0 += x1; x1 = rotl32(x1, 15); x1 ^= x0;
    x0 += x1; x1 = rotl32(x1, 26); x1 ^= x0;
    x0 += x1; x1 = rotl32(x1, 6);  x1 ^= x0;
    x0 += ks2; x1 += ks0 + 5u;
}

__global__ void init_kernel(const float4* __restrict__ pois, float4* __restrict__ x,
                            float4* __restrict__ out, int n4) {
    int i = blockIdx.x * blockDim.x + threadIdx.x;
    if (i < n4) {
        float4 v = pois[i];
        x[i] = v;
        out[i] = make_float4(0.25f * v.x, 0.25f * v.y, 0.25f * v.z, 0.25f * v.w);
    }
}

// ---- CSR build: histogram -> exclusive scan (3 kernels) -> scatter ----

__global__ void hist_kernel(const int* __restrict__ rows, int* __restrict__ cnt, int nnz) {
    int i = blockIdx.x * blockDim.x + threadIdx.x;
    if (i < nnz) atomicAdd(&cnt[rows[i]], 1);
}

// Per-block exclusive scan of 1024-element chunks; block totals to bsum.
__global__ void scan1_kernel(const int* __restrict__ cnt, int* __restrict__ start,
                             int* __restrict__ bsum, int n) {
    __shared__ int lds[SCAN_BLOCK];
    int base = blockIdx.x * SCAN_CHUNK + threadIdx.x * SCAN_ITEMS;
    int v[SCAN_ITEMS];
    int s = 0;
#pragma unroll
    for (int i = 0; i < SCAN_ITEMS; ++i) {
        int idx = base + i;
        v[i] = (idx < n) ? cnt[idx] : 0;
        s += v[i];
    }
    lds[threadIdx.x] = s;
    __syncthreads();
    for (int off = 1; off < SCAN_BLOCK; off <<= 1) {
        int t = (threadIdx.x >= off) ? lds[threadIdx.x - off] : 0;
        __syncthreads();
        lds[threadIdx.x] += t;
        __syncthreads();
    }
    if (threadIdx.x == SCAN_BLOCK - 1) bsum[blockIdx.x] = lds[SCAN_BLOCK - 1];
    int run = (threadIdx.x == 0) ? 0 : lds[threadIdx.x - 1];
#pragma unroll
    for (int i = 0; i < SCAN_ITEMS; ++i) {
        int idx = base + i;
        if (idx < n) start[idx] = run;
        run += v[i];
    }
}

// Single-block exclusive scan of block sums (nb <= 256).
__global__ void scan2_kernel(int* __restrict__ bsum, int nb) {
    __shared__ int lds[SCAN_BLOCK];
    int v = (threadIdx.x < nb) ? bsum[threadIdx.x] : 0;
    lds[threadIdx.x] = v;
    __syncthreads();
    for (int off = 1; off < SCAN_BLOCK; off <<= 1) {
        int t = (threadIdx.x >= off) ? lds[threadIdx.x - off] : 0;
        __syncthreads();
        lds[threadIdx.x] += t;
        __syncthreads();
    }
    int excl = (threadIdx.x == 0) ? 0 : lds[threadIdx.x - 1];
    if (threadIdx.x < nb) bsum[threadIdx.x] = excl;
}

// Add block offsets; also seed the scatter work pointers.
__global__ void scan3_kernel(int* __restrict__ start, int* __restrict__ work,
                             const int* __restrict__ bsum, int n) {
    int off = bsum[blockIdx.x];
    int base = blockIdx.x * SCAN_CHUNK;
#pragma unroll
    for (int i = 0; i < SCAN_ITEMS; ++i) {
        int idx = base + i * SCAN_BLOCK + threadIdx.x;
        if (idx < n) {
            int s = start[idx] + off;
            start[idx] = s;
            work[idx] = s;
        }
    }
}

__global__ void scatter_kernel(const int* __restrict__ rows, const int* __restrict__ cols,
                               const float* __restrict__ vals, int* __restrict__ work,
                               int* __restrict__ cols_s, float* __restrict__ vals_s,
                               int nnz) {
    int i = blockIdx.x * blockDim.x + threadIdx.x;
    if (i < nnz) {
        int pos = atomicAdd(&work[rows[i]], 1);
        cols_s[pos] = cols[i];
        vals_s[pos] = vals[i];
    }
}

// ---- SpMM (gather, no atomics): one wave per row, lane = dim ----

__global__ void spmm_gather(const int* __restrict__ start, const int* __restrict__ cnt,
                            const int* __restrict__ cols_s, const float* __restrict__ vals_s,
                            const float* __restrict__ x, float* __restrict__ out, int nrows) {
    int wid = (blockIdx.x * blockDim.x + threadIdx.x) >> 6;
    int lane = threadIdx.x & 63;
    if (wid >= nrows) return;
    int s = start[wid];
    int e = s + cnt[wid];
    float acc = 0.0f;
    for (int j = s; j < e; ++j) {
        acc += vals_s[j] * x[(size_t)cols_s[j] * DIM + lane];
    }
    out[(size_t)wid * DIM + lane] = acc;
}

// Fused: row r of prop = HG_pu @ msg, then x[r] = dropout(prop + x[r]),
// out[r] += 0.25 * x[r]. One wave per P-row.
__global__ void spmm_fused(const int* __restrict__ start, const int* __restrict__ cnt,
                           const int* __restrict__ cols_s, const float* __restrict__ vals_s,
                           const float* __restrict__ msg, float* __restrict__ x,
                           float* __restrict__ out, uint32_t k0, uint32_t k1, int nrows) {
    int wid = (blockIdx.x * blockDim.x + threadIdx.x) >> 6;
    int lane = threadIdx.x & 63;
    if (wid >= nrows) return;
    int s = start[wid];
    int e = s + cnt[wid];
    float acc = 0.0f;
    for (int j = s; j < e; ++j) {
        acc += vals_s[j] * msg[(size_t)cols_s[j] * DIM + lane];
    }
    size_t idx = (size_t)wid * DIM + lane;
    float a = acc + x[idx];
    uint32_t hi = 0u, lo = (uint32_t)idx;   // partitionable threefry, count = flat idx
    threefry2x32(k0, k1, hi, lo);
    float nx = ((hi ^ lo) & 0x80000000u) ? 0.0f : 2.0f * a;
    x[idx] = nx;
    out[idx] += 0.25f * nx;
}

extern "C" void kernel_launch(void* const* d_in, const int* in_sizes, int n_in,
                              void* d_out, int out_size, void* d_ws, size_t ws_size,
                              hipStream_t stream) {
    const float* pois    = (const float*)d_in[0];
    const int*   up_rows = (const int*)d_in[1];
    const int*   up_cols = (const int*)d_in[2];
    const float* up_vals = (const float*)d_in[3];
    const int*   pu_rows = (const int*)d_in[4];
    const int*   pu_cols = (const int*)d_in[5];
    const float* pu_vals = (const float*)d_in[6];
    float* out = (float*)d_out;

    const int n   = in_sizes[0];           // P*DIM = 12,800,000
    const int nnz = in_sizes[1];           // 2,000,000
    const int P   = n / DIM;               // 200,000
    const int U   = 50000;                 // fixed by problem
    const int mU  = U * DIM;               // 3,200,000

    // workspace layout (4-byte elements)
    float* x      = (float*)d_ws;                  // [n]
    float* msg    = x + n;                         // [mU]
    int*   u_start = (int*)(msg + mU);             // [U]
    int*   u_cnt   = u_start + U;                  // [U]
    int*   u_work  = u_cnt + U;                    // [U]
    int*   u_cols  = u_work + U;                   // [nnz]
    float* u_vals  = (float*)(u_cols + nnz);       // [nnz]
    int*   p_start = (int*)(u_vals + nnz);         // [P]
    int*   p_cnt   = p_start + P;                  // [P]
    int*   p_work  = p_cnt + P;                    // [P]
    int*   p_cols  = p_work + P;                   // [nnz]
    float* p_vals  = (float*)(p_cols + nnz);       // [nnz]
    int*   bsum    = (int*)(p_vals + nnz);         // [256]

    const int n4 = n / 4;
    init_kernel<<<(n4 + 255) / 256, 256, 0, stream>>>(
        (const float4*)pois, (float4*)x, (float4*)out, n4);

    const int nzb = (nnz + 255) / 256;

    // ---- build up CSR (U rows) ----
    hipMemsetAsync(u_cnt, 0, (size_t)U * sizeof(int), stream);
    hist_kernel<<<nzb, 256, 0, stream>>>(up_rows, u_cnt, nnz);
    int nbU = (U + SCAN_CHUNK - 1) / SCAN_CHUNK;   // 49
    scan1_kernel<<<nbU, SCAN_BLOCK, 0, stream>>>(u_cnt, u_start, bsum, U);
    scan2_kernel<<<1, SCAN_BLOCK, 0, stream>>>(bsum, nbU);
    scan3_kernel<<<nbU, SCAN_BLOCK, 0, stream>>>(u_start, u_work, bsum, U);
    scatter_kernel<<<nzb, 256, 0, stream>>>(up_rows, up_cols, up_vals, u_work,
                                            u_cols, u_vals, nnz);

    // ---- build pu CSR (P rows) ----
    hipMemsetAsync(p_cnt, 0, (size_t)P * sizeof(int), stream);
    hist_kernel<<<nzb, 256, 0, stream>>>(pu_rows, p_cnt, nnz);
    int nbP = (P + SCAN_CHUNK - 1) / SCAN_CHUNK;   // 196
    scan1_kernel<<<nbP, SCAN_BLOCK, 0, stream>>>(p_cnt, p_start, bsum, P);
    scan2_kernel<<<1, SCAN_BLOCK, 0, stream>>>(bsum, nbP);
    scan3_kernel<<<nbP, SCAN_BLOCK, 0, stream>>>(p_start, p_work, bsum, P);
    scatter_kernel<<<nzb, 256, 0, stream>>>(pu_rows, pu_cols, pu_vals, p_work,
                                            p_cols, p_vals, nnz);

    // ---- 3 layers ----
    const int gU = (U * 64 + 255) / 256;   // 4 rows (waves) per block
    const int gP = (P * 64 + 255) / 256;
    for (int l = 0; l < 3; ++l) {
        spmm_gather<<<gU, 256, 0, stream>>>(u_start, u_cnt, u_cols, u_vals,
                                            x, msg, U);
        uint32_t kk0 = 0u, kk1 = (uint32_t)l;
        threefry2x32(0u, 42u, kk0, kk1);   // key_l = fold_in(key(42), l)
        spmm_fused<<<gP, 256, 0, stream>>>(p_start, p_cnt, p_cols, p_vals,
                                           msg, x, out, kk0, kk1, P);
    }
}

// Round 5
// 1108.967 us; speedup vs baseline: 2.5866x; 1.5445x over previous
//
#include <hip/hip_runtime.h>
#include <stdint.h>

// MultiViewHyperConvNetwork: P=200000, U=50000, NNZ=2e6, D=64, 3 layers,
// dropout 0.5 (JAX partitionable threefry), key(42) fold_in(layer).
//
// Round-4: gather SpMM with 8x MLP — wave handles 4 nnz/iter (16 lanes x
// float4 per column-row), unrolled x2 (8 nnz, 2 gathers in flight/lane).
// Row reduce via __shfl_xor(16,32). Fused P-side epilogue redistributes the
// reduced float4 to one scalar element per lane for threefry dropout.

#define DIM 64
#define SCAN_BLOCK 256
#define SCAN_ITEMS 4
#define SCAN_CHUNK (SCAN_BLOCK * SCAN_ITEMS)

__host__ __device__ __forceinline__ uint32_t rotl32(uint32_t v, int d) {
    return (v << d) | (v >> (32 - d));
}

// Threefry-2x32, 20 rounds — bit-exact match to JAX's threefry2x32_p.
__host__ __device__ __forceinline__ void threefry2x32(uint32_t k0, uint32_t k1,
                                                      uint32_t& x0, uint32_t& x1) {
    const uint32_t ks0 = k0, ks1 = k1, ks2 = k0 ^ k1 ^ 0x1BD11BDAu;
    x0 += ks0; x1 += ks1;
    x0 += x1; x1 = rotl32(x1, 13); x1 ^= x0;
    x0 += x1; x1 = rotl32(x1, 15); x1 ^= x0;
    x0 += x1; x1 = rotl32(x1, 26); x1 ^= x0;
    x0 += x1; x1 = rotl32(x1, 6);  x1 ^= x0;
    x0 += ks1; x1 += ks2 + 1u;
    x0 += x1; x1 = rotl32(x1, 17); x1 ^= x0;
    x0 += x1; x1 = rotl32(x1, 29); x1 ^= x0;
    x0 += x1; x1 = rotl32(x1, 16); x1 ^= x0;
    x0 += x1; x1 = rotl32(x1, 24); x1 ^= x0;
    x0 += ks2; x1 += ks0 + 2u;
    x0 += x1; x1 = rotl32(x1, 13); x1 ^= x0;
    x0 += x1; x1 = rotl32(x1, 15); x1 ^= x0;
    x0 += x1; x1 = rotl32(x1, 26); x1 ^= x0;
    x0 += x1; x1 = rotl32(x1, 6);  x1 ^= x0;
    x0 += ks0; x1 += ks1 + 3u;
    x0 += x1; x1 = rotl32(x1, 17); x1 ^= x0;
    x0 += x1; x1 = rotl32(x1, 29); x1 ^= x0;
    x0 += x1; x1 = rotl32(x1, 16); x1 ^= x0;
    x0 += x1; x1 = rotl32(x1, 24); x1 ^= x0;
    x0 += ks1; x1 += ks2 + 4u;
    x0 += x1; x1 = rotl32(x1, 13); x1 ^= x0;
    x0 += x1; x1 = rotl32(x1, 15); x1 ^= x0;
    x0 += x1; x1 = rotl32(x1, 26); x1 ^= x0;
    x0 += x1; x1 = rotl32(x1, 6);  x1 ^= x0;
    x0 += ks2; x1 += ks0 + 5u;
}

__global__ void init_kernel(const float4* __restrict__ pois, float4* __restrict__ x,
                            float4* __restrict__ out, int n4) {
    int i = blockIdx.x * blockDim.x + threadIdx.x;
    if (i < n4) {
        float4 v = pois[i];
        x[i] = v;
        out[i] = make_float4(0.25f * v.x, 0.25f * v.y, 0.25f * v.z, 0.25f * v.w);
    }
}

// ---- CSR build: histogram -> exclusive scan (3 kernels) -> scatter ----

__global__ void hist_kernel(const int* __restrict__ rows, int* __restrict__ cnt, int nnz) {
    int i = blockIdx.x * blockDim.x + threadIdx.x;
    if (i < nnz) atomicAdd(&cnt[rows[i]], 1);
}

__global__ void scan1_kernel(const int* __restrict__ cnt, int* __restrict__ start,
                             int* __restrict__ bsum, int n) {
    __shared__ int lds[SCAN_BLOCK];
    int base = blockIdx.x * SCAN_CHUNK + threadIdx.x * SCAN_ITEMS;
    int v[SCAN_ITEMS];
    int s = 0;
#pragma unroll
    for (int i = 0; i < SCAN_ITEMS; ++i) {
        int idx = base + i;
        v[i] = (idx < n) ? cnt[idx] : 0;
        s += v[i];
    }
    lds[threadIdx.x] = s;
    __syncthreads();
    for (int off = 1; off < SCAN_BLOCK; off <<= 1) {
        int t = (threadIdx.x >= off) ? lds[threadIdx.x - off] : 0;
        __syncthreads();
        lds[threadIdx.x] += t;
        __syncthreads();
    }
    if (threadIdx.x == SCAN_BLOCK - 1) bsum[blockIdx.x] = lds[SCAN_BLOCK - 1];
    int run = (threadIdx.x == 0) ? 0 : lds[threadIdx.x - 1];
#pragma unroll
    for (int i = 0; i < SCAN_ITEMS; ++i) {
        int idx = base + i;
        if (idx < n) start[idx] = run;
        run += v[i];
    }
}

__global__ void scan2_kernel(int* __restrict__ bsum, int nb) {
    __shared__ int lds[SCAN_BLOCK];
    int v = (threadIdx.x < nb) ? bsum[threadIdx.x] : 0;
    lds[threadIdx.x] = v;
    __syncthreads();
    for (int off = 1; off < SCAN_BLOCK; off <<= 1) {
        int t = (threadIdx.x >= off) ? lds[threadIdx.x - off] : 0;
        __syncthreads();
        lds[threadIdx.x] += t;
        __syncthreads();
    }
    int excl = (threadIdx.x == 0) ? 0 : lds[threadIdx.x - 1];
    if (threadIdx.x < nb) bsum[threadIdx.x] = excl;
}

__global__ void scan3_kernel(int* __restrict__ start, int* __restrict__ work,
                             const int* __restrict__ bsum, int n) {
    int off = bsum[blockIdx.x];
    int base = blockIdx.x * SCAN_CHUNK;
#pragma unroll
    for (int i = 0; i < SCAN_ITEMS; ++i) {
        int idx = base + i * SCAN_BLOCK + threadIdx.x;
        if (idx < n) {
            int s = start[idx] + off;
            start[idx] = s;
            work[idx] = s;
        }
    }
}

__global__ void scatter_kernel(const int* __restrict__ rows, const int* __restrict__ cols,
                               const float* __restrict__ vals, int* __restrict__ work,
                               int* __restrict__ cols_s, float* __restrict__ vals_s,
                               int nnz) {
    int i = blockIdx.x * blockDim.x + threadIdx.x;
    if (i < nnz) {
        int pos = atomicAdd(&work[rows[i]], 1);
        cols_s[pos] = cols[i];
        vals_s[pos] = vals[i];
    }
}

// ---- SpMM gather, high-MLP: wave per row, 4 nnz/iter x2 unroll ----
// lane = (sub = lane>>4 -> nnz slot, d4 = lane&15 -> float4 within row)

__device__ __forceinline__ float4 shfl_xor_add4(float4 a, int mask) {
    a.x += __shfl_xor(a.x, mask, 64);
    a.y += __shfl_xor(a.y, mask, 64);
    a.z += __shfl_xor(a.z, mask, 64);
    a.w += __shfl_xor(a.w, mask, 64);
    return a;
}

__device__ __forceinline__ float4 row_accumulate(const int* __restrict__ cols_s,
                                                 const float* __restrict__ vals_s,
                                                 const float4* __restrict__ src4,
                                                 int s, int c, int sub, int d4) {
    float4 acc = make_float4(0.f, 0.f, 0.f, 0.f);
    int j = sub;
    for (; j + 4 < c; j += 8) {
        int  c0 = cols_s[s + j];
        float v0 = vals_s[s + j];
        int  c1 = cols_s[s + j + 4];
        float v1 = vals_s[s + j + 4];
        float4 g0 = src4[(size_t)c0 * 16 + d4];
        float4 g1 = src4[(size_t)c1 * 16 + d4];
        acc.x += v0 * g0.x + v1 * g1.x;
        acc.y += v0 * g0.y + v1 * g1.y;
        acc.z += v0 * g0.z + v1 * g1.z;
        acc.w += v0 * g0.w + v1 * g1.w;
    }
    if (j < c) {
        int  c0 = cols_s[s + j];
        float v0 = vals_s[s + j];
        float4 g0 = src4[(size_t)c0 * 16 + d4];
        acc.x += v0 * g0.x;
        acc.y += v0 * g0.y;
        acc.z += v0 * g0.z;
        acc.w += v0 * g0.w;
    }
    // reduce across the 4 sub slots (lanes l, l^16, l^32, l^48)
    acc = shfl_xor_add4(acc, 16);
    acc = shfl_xor_add4(acc, 32);
    return acc;
}

// msg = HG_up @ x : one wave per U-row.
__global__ void spmm_gather(const int* __restrict__ start, const int* __restrict__ cnt,
                            const int* __restrict__ cols_s, const float* __restrict__ vals_s,
                            const float4* __restrict__ x4, float4* __restrict__ out4,
                            int nrows) {
    int wid = (blockIdx.x * blockDim.x + threadIdx.x) >> 6;
    int lane = threadIdx.x & 63;
    if (wid >= nrows) return;
    int sub = lane >> 4, d4 = lane & 15;
    float4 acc = row_accumulate(cols_s, vals_s, x4, start[wid], cnt[wid], sub, d4);
    if (sub == 0) out4[(size_t)wid * 16 + d4] = acc;
}

// Fused P-side: prop_row = HG_pu @ msg; x = dropout(prop + x); out += x/4.
__global__ void spmm_fused(const int* __restrict__ start, const int* __restrict__ cnt,
                           const int* __restrict__ cols_s, const float* __restrict__ vals_s,
                           const float4* __restrict__ msg4, float* __restrict__ x,
                           float* __restrict__ out, uint32_t k0, uint32_t k1, int nrows) {
    int wid = (blockIdx.x * blockDim.x + threadIdx.x) >> 6;
    int lane = threadIdx.x & 63;
    if (wid >= nrows) return;
    int sub = lane >> 4, d4 = lane & 15;
    float4 acc = row_accumulate(cols_s, vals_s, msg4, start[wid], cnt[wid], sub, d4);
    // redistribute: lane l takes scalar element l of the row.
    // element l lives in float4 index (l>>2), component (l&3); all sub groups
    // hold identical reduced copies, so src lane = l>>2 works.
    int srcl = lane >> 2;
    float a0 = __shfl(acc.x, srcl, 64);
    float a1 = __shfl(acc.y, srcl, 64);
    float a2 = __shfl(acc.z, srcl, 64);
    float a3 = __shfl(acc.w, srcl, 64);
    int comp = lane & 3;
    float av = (comp & 2) ? ((comp & 1) ? a3 : a2) : ((comp & 1) ? a1 : a0);
    size_t idx = (size_t)wid * DIM + lane;
    float a = av + x[idx];
    uint32_t hi = 0u, lo = (uint32_t)idx;   // partitionable threefry, count = flat idx
    threefry2x32(k0, k1, hi, lo);
    float nx = ((hi ^ lo) & 0x80000000u) ? 0.0f : 2.0f * a;
    x[idx] = nx;
    out[idx] += 0.25f * nx;
}

extern "C" void kernel_launch(void* const* d_in, const int* in_sizes, int n_in,
                              void* d_out, int out_size, void* d_ws, size_t ws_size,
                              hipStream_t stream) {
    const float* pois    = (const float*)d_in[0];
    const int*   up_rows = (const int*)d_in[1];
    const int*   up_cols = (const int*)d_in[2];
    const float* up_vals = (const float*)d_in[3];
    const int*   pu_rows = (const int*)d_in[4];
    const int*   pu_cols = (const int*)d_in[5];
    const float* pu_vals = (const float*)d_in[6];
    float* out = (float*)d_out;

    const int n   = in_sizes[0];           // P*DIM = 12,800,000
    const int nnz = in_sizes[1];           // 2,000,000
    const int P   = n / DIM;               // 200,000
    const int U   = 50000;                 // fixed by problem
    const int mU  = U * DIM;               // 3,200,000

    // workspace layout (4-byte elements)
    float* x      = (float*)d_ws;                  // [n]
    float* msg    = x + n;                         // [mU]
    int*   u_start = (int*)(msg + mU);             // [U]
    int*   u_cnt   = u_start + U;                  // [U]
    int*   u_work  = u_cnt + U;                    // [U]
    int*   u_cols  = u_work + U;                   // [nnz]
    float* u_vals  = (float*)(u_cols + nnz);       // [nnz]
    int*   p_start = (int*)(u_vals + nnz);         // [P]
    int*   p_cnt   = p_start + P;                  // [P]
    int*   p_work  = p_cnt + P;                    // [P]
    int*   p_cols  = p_work + P;                   // [nnz]
    float* p_vals  = (float*)(p_cols + nnz);       // [nnz]
    int*   bsum    = (int*)(p_vals + nnz);         // [256]

    const int n4 = n / 4;
    init_kernel<<<(n4 + 255) / 256, 256, 0, stream>>>(
        (const float4*)pois, (float4*)x, (float4*)out, n4);

    const int nzb = (nnz + 255) / 256;

    // ---- build up CSR (U rows) ----
    hipMemsetAsync(u_cnt, 0, (size_t)U * sizeof(int), stream);
    hist_kernel<<<nzb, 256, 0, stream>>>(up_rows, u_cnt, nnz);
    int nbU = (U + SCAN_CHUNK - 1) / SCAN_CHUNK;   // 49
    scan1_kernel<<<nbU, SCAN_BLOCK, 0, stream>>>(u_cnt, u_start, bsum, U);
    scan2_kernel<<<1, SCAN_BLOCK, 0, stream>>>(bsum, nbU);
    scan3_kernel<<<nbU, SCAN_BLOCK, 0, stream>>>(u_start, u_work, bsum, U);
    scatter_kernel<<<nzb, 256, 0, stream>>>(up_rows, up_cols, up_vals, u_work,
                                            u_cols, u_vals, nnz);

    // ---- build pu CSR (P rows) ----
    hipMemsetAsync(p_cnt, 0, (size_t)P * sizeof(int), stream);
    hist_kernel<<<nzb, 256, 0, stream>>>(pu_rows, p_cnt, nnz);
    int nbP = (P + SCAN_CHUNK - 1) / SCAN_CHUNK;   // 196
    scan1_kernel<<<nbP, SCAN_BLOCK, 0, stream>>>(p_cnt, p_start, bsum, P);
    scan2_kernel<<<1, SCAN_BLOCK, 0, stream>>>(bsum, nbP);
    scan3_kernel<<<nbP, SCAN_BLOCK, 0, stream>>>(p_start, p_work, bsum, P);
    scatter_kernel<<<nzb, 256, 0, stream>>>(pu_rows, pu_cols, pu_vals, p_work,
                                            p_cols, p_vals, nnz);

    // ---- 3 layers ----
    const long long thU = (long long)U * 64;
    const long long thP = (long long)P * 64;
    const int gU = (int)((thU + 255) / 256);
    const int gP = (int)((thP + 255) / 256);
    for (int l = 0; l < 3; ++l) {
        spmm_gather<<<gU, 256, 0, stream>>>(u_start, u_cnt, u_cols, u_vals,
                                            (const float4*)x, (float4*)msg, U);
        uint32_t kk0 = 0u, kk1 = (uint32_t)l;
        threefry2x32(0u, 42u, kk0, kk1);   // key_l = fold_in(key(42), l)
        spmm_fused<<<gP, 256, 0, stream>>>(p_start, p_cnt, p_cols, p_vals,
                                           (const float4*)msg, x, out, kk0, kk1, P);
    }
}